// Round 1
// baseline (909.604 us; speedup 1.0000x reference)
//
#include <hip/hip_runtime.h>
#include <cstdint>
#include <cstddef>

#define S_LEN 2048
#define H_DIM 4096
#define NHEAD 32
#define HD    128
#define N_QKV 12288
#define INV_NORM 0.08838834764831845f  // 1/sqrt(128)

typedef __bf16 bf16_t;
typedef bf16_t bf16x8 __attribute__((ext_vector_type(8)));
typedef bf16_t bf16x4 __attribute__((ext_vector_type(4)));
typedef float  f32x4  __attribute__((ext_vector_type(4)));

static_assert(sizeof(bf16x8) == 16, "bf16x8 must be 16B");

__device__ __forceinline__ f32x4 mfma16(bf16x8 a, bf16x8 b, f32x4 c) {
  return __builtin_amdgcn_mfma_f32_16x16x32_bf16(a, b, c, 0, 0, 0);
}

// async global->LDS, 16B per lane. LDS dest must be wave-uniform base; HW adds lane*16.
typedef __attribute__((address_space(1))) void gas_void;
typedef __attribute__((address_space(3))) void las_void;
__device__ __forceinline__ void async16(const void* g, void* l) {
  __builtin_amdgcn_global_load_lds((const gas_void*)g,
                                   (las_void*)(uint32_t)(uintptr_t)l,
                                   16, 0, 0);
}

// ---------------- fp32 -> bf16 conversion (vectorized) ----------------
typedef float f32v4 __attribute__((ext_vector_type(4)));
__global__ void cvt_f32_bf16(const float* __restrict__ in, bf16_t* __restrict__ out, int n4) {
  int i = blockIdx.x * 256 + threadIdx.x;
  if (i >= n4) return;
  f32v4 v = ((const f32v4*)in)[i];
  bf16x4 r;
  r[0] = (bf16_t)v[0]; r[1] = (bf16_t)v[1]; r[2] = (bf16_t)v[2]; r[3] = (bf16_t)v[3];
  ((bf16x4*)out)[i] = r;
}

// ---------------- GEMM: C = A(MxK) * B(NxK)^T, 128x128 tile, BK=32 ----------------
// MODE 0: QKV epilogue -> scatter to Q (scaled by INV_NORM), K, V buffers [NH][S][HD] bf16
// MODE 1: dense epilogue -> fp32 out = acc + bias + residual
template <int MODE>
__global__ void gemm_bt(const bf16_t* __restrict__ A,
                        const bf16_t* __restrict__ B,
                        const float* __restrict__ bias,
                        const float* __restrict__ residual,
                        bf16_t* __restrict__ q_out,
                        bf16_t* __restrict__ k_out,
                        bf16_t* __restrict__ v_out,
                        float* __restrict__ f_out,
                        int Kdim)
{
  __shared__ bf16_t As[128 * 32];
  __shared__ bf16_t Bs[128 * 32];
  const int tid  = threadIdx.x;
  const int lane = tid & 63;
  const int w    = tid >> 6;
  const int wr   = w >> 1, wc = w & 1;
  const int lo   = lane & 15, g = lane >> 4;
  const int brow = blockIdx.y * 128;
  const int bcol = blockIdx.x * 128;

  // staging geometry: LDS linear [128 rows][32 k] bf16 (64B per row)
  const int oA   = w * 1024 + lane * 16;   // byte offset within 4KB half
  const int rowS = oA >> 6;                // 0..63
  const int kEl  = (oA & 63) >> 1;         // element offset 0..24

  const bf16_t* aP0 = A + (size_t)(brow + rowS) * Kdim + kEl;
  const bf16_t* aP1 = A + (size_t)(brow + rowS + 64) * Kdim + kEl;
  const bf16_t* bP0 = B + (size_t)(bcol + rowS) * Kdim + kEl;
  const bf16_t* bP1 = B + (size_t)(bcol + rowS + 64) * Kdim + kEl;

  char* AsB = (char*)As;
  char* BsB = (char*)Bs;
  char* ldsA0 = AsB + w * 1024;
  char* ldsA1 = AsB + 4096 + w * 1024;
  char* ldsB0 = BsB + w * 1024;
  char* ldsB1 = BsB + 4096 + w * 1024;

  f32x4 acc[4][4] = {};

  for (int kk = 0; kk < Kdim; kk += 32) {
    async16(aP0, ldsA0);
    async16(aP1, ldsA1);
    async16(bP0, ldsB0);
    async16(bP1, ldsB1);
    aP0 += 32; aP1 += 32; bP0 += 32; bP1 += 32;
    __syncthreads();   // compiler drains vmcnt before barrier -> LDS tiles valid
    bf16x8 af[4], bfr[4];
#pragma unroll
    for (int i = 0; i < 4; i++)
      af[i] = *(const bf16x8*)(AsB + ((wr * 64 + i * 16 + lo) * 64 + g * 16));
#pragma unroll
    for (int j = 0; j < 4; j++)
      bfr[j] = *(const bf16x8*)(BsB + ((wc * 64 + j * 16 + lo) * 64 + g * 16));
#pragma unroll
    for (int i = 0; i < 4; i++)
#pragma unroll
      for (int j = 0; j < 4; j++)
        acc[i][j] = mfma16(af[i], bfr[j], acc[i][j]);
    __syncthreads();   // protect LDS from next-iter staging
  }

  if (MODE == 0) {
    // column chunk of 128 maps to exactly one (head, qkv-slot)
    const int chunk = bcol >> 7;        // 0..95
    const int t = chunk % 3, h = chunk / 3;
    bf16_t* dst = (t == 0) ? q_out : (t == 1) ? k_out : v_out;
    dst += (size_t)h * S_LEN * HD;
    const float scale = (t == 0) ? INV_NORM : 1.0f;
#pragma unroll
    for (int i = 0; i < 4; i++) {
#pragma unroll
      for (int j = 0; j < 4; j++) {
        const int d = wc * 64 + j * 16 + lo;       // 0..127 within head-dim
        const float bb = bias[bcol + d];
#pragma unroll
        for (int jj = 0; jj < 4; jj++) {
          const int r = brow + wr * 64 + i * 16 + g * 4 + jj;
          dst[(size_t)r * HD + d] = (bf16_t)((acc[i][j][jj] + bb) * scale);
        }
      }
    }
  } else {
#pragma unroll
    for (int i = 0; i < 4; i++) {
#pragma unroll
      for (int j = 0; j < 4; j++) {
        const int c = bcol + wc * 64 + j * 16 + lo;
        const float bb = bias[c];
#pragma unroll
        for (int jj = 0; jj < 4; jj++) {
          const int r = brow + wr * 64 + i * 16 + g * 4 + jj;
          f_out[(size_t)r * H_DIM + c] = acc[i][j][jj] + bb + residual[(size_t)r * H_DIM + c];
        }
      }
    }
  }
}

// ---------------- Flash attention w/ ALiBi + causal mask ----------------
// Grid: 32 heads x 16 q-blocks (128 rows). 4 waves, each owns 32 q-rows.
// Q hoisted to regs (pre-scaled by INV_NORM). K B-frags straight from global (L2).
// V staged transposed into padded LDS. P via per-wave padded LDS (C-layout -> A-layout).
__global__ void attn_kernel(const bf16_t* __restrict__ Qg,
                            const bf16_t* __restrict__ Kg,
                            const bf16_t* __restrict__ Vg,
                            const float* __restrict__ alibi,
                            bf16_t* __restrict__ ctx)
{
  const int h  = blockIdx.x & 31;
  const int qb = blockIdx.x >> 5;
  const int tid = threadIdx.x, lane = tid & 63, w = tid >> 6;
  const int lo = lane & 15, g = lane >> 4;

  __shared__ bf16_t Vt[128][72];      // [d][k], pad 72 to break bank conflicts
  __shared__ bf16_t Pl[4][32][72];    // per-wave P [q][k]

  const bf16_t* Qh = Qg + ((size_t)h * S_LEN + qb * 128 + w * 32) * HD;
  const bf16_t* Kh = Kg + (size_t)h * S_LEN * HD;
  const bf16_t* Vh = Vg + (size_t)h * S_LEN * HD;
  const float* al_h = alibi + h * S_LEN;

  bf16x8 qf[2][4];
#pragma unroll
  for (int rf = 0; rf < 2; rf++)
#pragma unroll
    for (int ds = 0; ds < 4; ds++)
      qf[rf][ds] = *(const bf16x8*)(Qh + (rf * 16 + lo) * HD + ds * 32 + g * 8);

  f32x4 oacc[2][8] = {};
  float m_r[2][4], l_r[2][4];
#pragma unroll
  for (int rf = 0; rf < 2; rf++)
#pragma unroll
    for (int jj = 0; jj < 4; jj++) { m_r[rf][jj] = -INFINITY; l_r[rf][jj] = 0.f; }

  const int ntiles = 2 * (qb + 1);
  const int q_base = qb * 128 + w * 32;

  for (int kt = 0; kt < ntiles; ++kt) {
    const int k0 = kt * 64;

    // ---- stage V^T tile: V[k0+kv][d] -> Vt[d][kv]
#pragma unroll
    for (int u = 0; u < 4; ++u) {
      const int idx = u * 256 + tid;
      const int kv = idx >> 4;
      const int d0 = (idx & 15) << 3;
      bf16x8 vv = *(const bf16x8*)(Vh + (size_t)(k0 + kv) * HD + d0);
#pragma unroll
      for (int e = 0; e < 8; ++e) Vt[d0 + e][kv] = vv[e];
    }

    float al[4];
#pragma unroll
    for (int kc = 0; kc < 4; kc++) al[kc] = al_h[k0 + kc * 16 + lo];

    // ---- QK^T (B-frags from global K, 2-deep manual prefetch)
    f32x4 sacc[2][4] = {};
    bf16x8 kfA[4], kfB[4];
#pragma unroll
    for (int ds = 0; ds < 4; ++ds)
      kfA[ds] = *(const bf16x8*)(Kh + (size_t)(k0 + lo) * HD + ds * 32 + g * 8);
#pragma unroll
    for (int kc = 0; kc < 4; ++kc) {
      if (kc < 3) {
#pragma unroll
        for (int ds = 0; ds < 4; ++ds)
          kfB[ds] = *(const bf16x8*)(Kh + (size_t)(k0 + (kc + 1) * 16 + lo) * HD + ds * 32 + g * 8);
      }
#pragma unroll
      for (int ds = 0; ds < 4; ++ds) {
        sacc[0][kc] = mfma16(qf[0][ds], kfA[ds], sacc[0][kc]);
        sacc[1][kc] = mfma16(qf[1][ds], kfA[ds], sacc[1][kc]);
      }
#pragma unroll
      for (int ds = 0; ds < 4; ++ds) kfA[ds] = kfB[ds];
    }

    // ---- scores = qk + alibi, causal mask in diagonal tiles
    float sv[2][4][4];
#pragma unroll
    for (int rf = 0; rf < 2; rf++)
#pragma unroll
      for (int kc = 0; kc < 4; kc++)
#pragma unroll
        for (int jj = 0; jj < 4; jj++)
          sv[rf][kc][jj] = sacc[rf][kc][jj] + al[kc];
    if (kt >= ntiles - 2) {
#pragma unroll
      for (int rf = 0; rf < 2; rf++)
#pragma unroll
        for (int kc = 0; kc < 4; kc++) {
          const int k_gl = k0 + kc * 16 + lo;
#pragma unroll
          for (int jj = 0; jj < 4; jj++) {
            const int q_gl = q_base + rf * 16 + g * 4 + jj;
            if (k_gl > q_gl) sv[rf][kc][jj] = -INFINITY;
          }
        }
    }

    // ---- online softmax (rows live in C-layout: row = g*4+jj (+16*rf), cols across lane&15)
#pragma unroll
    for (int rf = 0; rf < 2; rf++) {
#pragma unroll
      for (int jj = 0; jj < 4; jj++) {
        float mx = fmaxf(fmaxf(sv[rf][0][jj], sv[rf][1][jj]), fmaxf(sv[rf][2][jj], sv[rf][3][jj]));
        mx = fmaxf(mx, __shfl_xor(mx, 1, 64));
        mx = fmaxf(mx, __shfl_xor(mx, 2, 64));
        mx = fmaxf(mx, __shfl_xor(mx, 4, 64));
        mx = fmaxf(mx, __shfl_xor(mx, 8, 64));
        const float mn = fmaxf(m_r[rf][jj], mx);
        const float sc = __expf(m_r[rf][jj] - mn);
        m_r[rf][jj] = mn;
        l_r[rf][jj] *= sc;
#pragma unroll
        for (int df = 0; df < 8; df++) oacc[rf][df][jj] *= sc;
        float rs = 0.f;
#pragma unroll
        for (int kc = 0; kc < 4; kc++) {
          const float p = __expf(sv[rf][kc][jj] - mn);
          rs += p;
          Pl[w][rf * 16 + g * 4 + jj][kc * 16 + lo] = (bf16_t)p;
        }
        rs += __shfl_xor(rs, 1, 64);
        rs += __shfl_xor(rs, 2, 64);
        rs += __shfl_xor(rs, 4, 64);
        rs += __shfl_xor(rs, 8, 64);
        l_r[rf][jj] += rs;
      }
    }

    __syncthreads();   // Vt staged (all waves) + P writes drained (lgkmcnt)

    // ---- PV: oacc += P(32x64) * V(64x128)
#pragma unroll
    for (int ks = 0; ks < 2; ++ks) {
      bf16x8 pa[2];
      pa[0] = *(const bf16x8*)&Pl[w][lo][ks * 32 + g * 8];
      pa[1] = *(const bf16x8*)&Pl[w][16 + lo][ks * 32 + g * 8];
#pragma unroll
      for (int df = 0; df < 8; df++) {
        bf16x8 vf = *(const bf16x8*)&Vt[df * 16 + lo][ks * 32 + g * 8];
        oacc[0][df] = mfma16(pa[0], vf, oacc[0][df]);
        oacc[1][df] = mfma16(pa[1], vf, oacc[1][df]);
      }
    }
    __syncthreads();   // protect Vt before next-tile staging
  }

  // ---- finalize: divide by l, write ctx [S][H] bf16
#pragma unroll
  for (int rf = 0; rf < 2; rf++) {
#pragma unroll
    for (int jj = 0; jj < 4; jj++) {
      const float inv = 1.0f / l_r[rf][jj];
      const int r = q_base + rf * 16 + g * 4 + jj;
#pragma unroll
      for (int df = 0; df < 8; df++) {
        const int d = df * 16 + lo;
        ctx[(size_t)r * H_DIM + h * HD + d] = (bf16_t)(oacc[rf][df][jj] * inv);
      }
    }
  }
}

// ---------------- launch ----------------
extern "C" void kernel_launch(void* const* d_in, const int* in_sizes, int n_in,
                              void* d_out, int out_size, void* d_ws, size_t ws_size,
                              hipStream_t stream) {
  const float* hidden   = (const float*)d_in[0];
  const float* residual = (const float*)d_in[1];
  const float* alibi    = (const float*)d_in[2];
  // d_in[3] attention_mask: analytic (triu k=1 == causal), unused
  const float* w_qkv    = (const float*)d_in[4];
  const float* b_qkv    = (const float*)d_in[5];
  const float* w_dense  = (const float*)d_in[6];
  const float* b_dense  = (const float*)d_in[7];
  float* out = (float*)d_out;

  char* ws = (char*)d_ws;
  // layout (bytes): total 218,103,808
  bf16_t* Xb  = (bf16_t*)(ws);                 // 2048*4096*2      = 16,777,216
  bf16_t* Wqb = (bf16_t*)(ws + 16777216);      // 12288*4096*2     = 100,663,296
  bf16_t* Wdb = (bf16_t*)(ws + 117440512);     // 4096*4096*2      = 33,554,432
  bf16_t* Qb  = (bf16_t*)(ws + 150994944);     // 32*2048*128*2    = 16,777,216
  bf16_t* Kb  = (bf16_t*)(ws + 167772160);
  bf16_t* Vb  = (bf16_t*)(ws + 184549376);
  bf16_t* Ctx = (bf16_t*)(ws + 201326592);

  // fp32 -> bf16 converts
  {
    int n4 = (S_LEN * H_DIM) / 4;        // 2,097,152
    cvt_f32_bf16<<<(n4 + 255) / 256, 256, 0, stream>>>(hidden, Xb, n4);
  }
  {
    int n4 = (N_QKV * H_DIM) / 4;        // 12,582,912
    cvt_f32_bf16<<<(n4 + 255) / 256, 256, 0, stream>>>(w_qkv, Wqb, n4);
  }
  {
    int n4 = (H_DIM * H_DIM) / 4;        // 4,194,304
    cvt_f32_bf16<<<(n4 + 255) / 256, 256, 0, stream>>>(w_dense, Wdb, n4);
  }

  // QKV GEMM: [2048 x 4096] @ [12288 x 4096]^T -> scatter Q(scaled)/K/V
  gemm_bt<0><<<dim3(N_QKV / 128, S_LEN / 128), 256, 0, stream>>>(
      Xb, Wqb, b_qkv, nullptr, Qb, Kb, Vb, nullptr, H_DIM);

  // attention
  attn_kernel<<<NHEAD * (S_LEN / 128), 256, 0, stream>>>(Qb, Kb, Vb, alibi, Ctx);

  // dense GEMM + bias + residual -> fp32 out
  gemm_bt<1><<<dim3(H_DIM / 128, S_LEN / 128), 256, 0, stream>>>(
      Ctx, Wdb, b_dense, residual, nullptr, nullptr, nullptr, out, H_DIM);
}

// Round 2
// 641.627 us; speedup vs baseline: 1.4177x; 1.4177x over previous
//
#include <hip/hip_runtime.h>
#include <cstdint>
#include <cstddef>

#define S_LEN 2048
#define H_DIM 4096
#define NHEAD 32
#define HD    128
#define N_QKV 12288
#define INV_NORM 0.08838834764831845f  // 1/sqrt(128)

typedef __bf16 bf16_t;
typedef bf16_t bf16x8 __attribute__((ext_vector_type(8)));
typedef bf16_t bf16x4 __attribute__((ext_vector_type(4)));
typedef float  f32x4  __attribute__((ext_vector_type(4)));

static_assert(sizeof(bf16x8) == 16, "bf16x8 must be 16B");

__device__ __forceinline__ f32x4 mfma16(bf16x8 a, bf16x8 b, f32x4 c) {
  return __builtin_amdgcn_mfma_f32_16x16x32_bf16(a, b, c, 0, 0, 0);
}

// async global->LDS, 16B per lane. LDS dest must be wave-uniform base; HW adds lane*16.
typedef __attribute__((address_space(1))) void gas_void;
typedef __attribute__((address_space(3))) void las_void;
__device__ __forceinline__ void async16(const void* g, void* l) {
  __builtin_amdgcn_global_load_lds((const gas_void*)g,
                                   (las_void*)(uint32_t)(uintptr_t)l,
                                   16, 0, 0);
}

// ---------------- fp32 -> bf16 conversion (vectorized) ----------------
typedef float f32v4 __attribute__((ext_vector_type(4)));
__global__ void cvt_f32_bf16(const float* __restrict__ in, bf16_t* __restrict__ out, int n4) {
  int i = blockIdx.x * 256 + threadIdx.x;
  if (i >= n4) return;
  f32v4 v = ((const f32v4*)in)[i];
  bf16x4 r;
  r[0] = (bf16_t)v[0]; r[1] = (bf16_t)v[1]; r[2] = (bf16_t)v[2]; r[3] = (bf16_t)v[3];
  ((bf16x4*)out)[i] = r;
}

// ---------------- GEMM: C = A(MxK) * B(NxK)^T, 128x128 tile, BK=32 ----------------
// MODE 0: QKV epilogue -> scatter to Q (scaled by INV_NORM), K, V buffers [NH][S][HD] bf16
// MODE 1: dense epilogue -> fp32 out = acc + bias + residual
template <int MODE>
__global__ void gemm_bt(const bf16_t* __restrict__ A,
                        const bf16_t* __restrict__ B,
                        const float* __restrict__ bias,
                        const float* __restrict__ residual,
                        bf16_t* __restrict__ q_out,
                        bf16_t* __restrict__ k_out,
                        bf16_t* __restrict__ v_out,
                        float* __restrict__ f_out,
                        int Kdim)
{
  __shared__ bf16_t As[128 * 32];
  __shared__ bf16_t Bs[128 * 32];
  const int tid  = threadIdx.x;
  const int lane = tid & 63;
  const int w    = tid >> 6;
  const int wr   = w >> 1, wc = w & 1;
  const int lo   = lane & 15, g = lane >> 4;
  const int brow = blockIdx.y * 128;
  const int bcol = blockIdx.x * 128;

  // staging geometry: LDS linear [128 rows][32 k] bf16 (64B per row)
  const int oA   = w * 1024 + lane * 16;   // byte offset within 4KB half
  const int rowS = oA >> 6;                // 0..63
  const int kEl  = (oA & 63) >> 1;         // element offset 0..24

  const bf16_t* aP0 = A + (size_t)(brow + rowS) * Kdim + kEl;
  const bf16_t* aP1 = A + (size_t)(brow + rowS + 64) * Kdim + kEl;
  const bf16_t* bP0 = B + (size_t)(bcol + rowS) * Kdim + kEl;
  const bf16_t* bP1 = B + (size_t)(bcol + rowS + 64) * Kdim + kEl;

  char* AsB = (char*)As;
  char* BsB = (char*)Bs;
  char* ldsA0 = AsB + w * 1024;
  char* ldsA1 = AsB + 4096 + w * 1024;
  char* ldsB0 = BsB + w * 1024;
  char* ldsB1 = BsB + 4096 + w * 1024;

  f32x4 acc[4][4] = {};

  for (int kk = 0; kk < Kdim; kk += 32) {
    async16(aP0, ldsA0);
    async16(aP1, ldsA1);
    async16(bP0, ldsB0);
    async16(bP1, ldsB1);
    aP0 += 32; aP1 += 32; bP0 += 32; bP1 += 32;
    __syncthreads();   // compiler drains vmcnt before barrier -> LDS tiles valid
    bf16x8 af[4], bfr[4];
#pragma unroll
    for (int i = 0; i < 4; i++)
      af[i] = *(const bf16x8*)(AsB + ((wr * 64 + i * 16 + lo) * 64 + g * 16));
#pragma unroll
    for (int j = 0; j < 4; j++)
      bfr[j] = *(const bf16x8*)(BsB + ((wc * 64 + j * 16 + lo) * 64 + g * 16));
#pragma unroll
    for (int i = 0; i < 4; i++)
#pragma unroll
      for (int j = 0; j < 4; j++)
        acc[i][j] = mfma16(af[i], bfr[j], acc[i][j]);
    __syncthreads();   // protect LDS from next-iter staging
  }

  if (MODE == 0) {
    // column chunk of 128 maps to exactly one (head, qkv-slot)
    const int chunk = bcol >> 7;        // 0..95
    const int t = chunk % 3, h = chunk / 3;
    bf16_t* dst = (t == 0) ? q_out : (t == 1) ? k_out : v_out;
    dst += (size_t)h * S_LEN * HD;
    const float scale = (t == 0) ? INV_NORM : 1.0f;
#pragma unroll
    for (int i = 0; i < 4; i++) {
#pragma unroll
      for (int j = 0; j < 4; j++) {
        const int d = wc * 64 + j * 16 + lo;       // 0..127 within head-dim
        const float bb = bias[bcol + d];
#pragma unroll
        for (int jj = 0; jj < 4; jj++) {
          const int r = brow + wr * 64 + i * 16 + g * 4 + jj;
          dst[(size_t)r * HD + d] = (bf16_t)((acc[i][j][jj] + bb) * scale);
        }
      }
    }
  } else {
#pragma unroll
    for (int i = 0; i < 4; i++) {
#pragma unroll
      for (int j = 0; j < 4; j++) {
        const int c = bcol + wc * 64 + j * 16 + lo;
        const float bb = bias[c];
#pragma unroll
        for (int jj = 0; jj < 4; jj++) {
          const int r = brow + wr * 64 + i * 16 + g * 4 + jj;
          f_out[(size_t)r * H_DIM + c] = acc[i][j][jj] + bb + residual[(size_t)r * H_DIM + c];
        }
      }
    }
  }
}

// ---------------- Flash attention w/ ALiBi + causal mask ----------------
// Grid: 1024 blocks = 32 q-blocks (64 rows, heavy-first) x 32 heads.
// 4 waves, each owns 16 q-rows. Q in regs (pre-scaled). K B-frags from global (L2).
// V^T staged in LDS with kv-major mapping (conflict-free writes). P via per-wave LDS.
__global__ void attn_kernel(const bf16_t* __restrict__ Qg,
                            const bf16_t* __restrict__ Kg,
                            const bf16_t* __restrict__ Vg,
                            const float* __restrict__ alibi,
                            bf16_t* __restrict__ ctx)
{
  const int h  = blockIdx.x & 31;
  const int qb = 31 - (blockIdx.x >> 5);      // heavy blocks first
  const int tid = threadIdx.x, lane = tid & 63, w = tid >> 6;
  const int lo = lane & 15, g = lane >> 4;

  __shared__ bf16_t Vt[128][72];      // [d][k], pad 72 (write mapping is kv-major: conflict-free)
  __shared__ bf16_t Pl[4][16][72];    // per-wave P [q][k]

  const bf16_t* Qh = Qg + ((size_t)h * S_LEN + qb * 64 + w * 16) * HD;
  const bf16_t* Kh = Kg + (size_t)h * S_LEN * HD;
  const bf16_t* Vh = Vg + (size_t)h * S_LEN * HD;
  const float* al_h = alibi + h * S_LEN;

  bf16x8 qf[4];
#pragma unroll
  for (int ds = 0; ds < 4; ds++)
    qf[ds] = *(const bf16x8*)(Qh + lo * HD + ds * 32 + g * 8);

  f32x4 oacc[8] = {};
  float m_r[4], l_r[4];
#pragma unroll
  for (int jj = 0; jj < 4; jj++) { m_r[jj] = -INFINITY; l_r[jj] = 0.f; }

  const int ntiles = qb + 1;          // 64-wide K tiles; diagonal is the last tile only
  const int q_base = qb * 64 + w * 16;

  for (int kt = 0; kt < ntiles; ++kt) {
    const int k0 = kt * 64;

    // ---- stage V^T tile: V[k0+kv][d] -> Vt[d][kv]; kv-major lanes -> LDS writes contiguous
#pragma unroll
    for (int u = 0; u < 4; ++u) {
      const int idx = u * 256 + tid;
      const int kv = idx & 63;
      const int d0 = (idx >> 6) * 8;          // 0..120
      bf16x8 vv = *(const bf16x8*)(Vh + (size_t)(k0 + kv) * HD + d0);
#pragma unroll
      for (int e = 0; e < 8; ++e) Vt[d0 + e][kv] = vv[e];
    }

    float al[4];
#pragma unroll
    for (int kc = 0; kc < 4; kc++) al[kc] = al_h[k0 + kc * 16 + lo];

    // ---- QK^T: B-frags straight from global K (L2-resident)
    f32x4 sacc[4] = {};
#pragma unroll
    for (int kc = 0; kc < 4; ++kc) {
      bf16x8 kf[4];
#pragma unroll
      for (int ds = 0; ds < 4; ++ds)
        kf[ds] = *(const bf16x8*)(Kh + (size_t)(k0 + kc * 16 + lo) * HD + ds * 32 + g * 8);
#pragma unroll
      for (int ds = 0; ds < 4; ++ds)
        sacc[kc] = mfma16(qf[ds], kf[ds], sacc[kc]);
    }

    // ---- scores = qk + alibi, causal mask only in the diagonal tile
    float sv[4][4];
#pragma unroll
    for (int kc = 0; kc < 4; kc++)
#pragma unroll
      for (int jj = 0; jj < 4; jj++)
        sv[kc][jj] = sacc[kc][jj] + al[kc];
    if (kt == ntiles - 1) {
#pragma unroll
      for (int kc = 0; kc < 4; kc++) {
        const int k_gl = k0 + kc * 16 + lo;
#pragma unroll
        for (int jj = 0; jj < 4; jj++) {
          const int q_gl = q_base + g * 4 + jj;
          if (k_gl > q_gl) sv[kc][jj] = -INFINITY;
        }
      }
    }

    // ---- online softmax (row = g*4+jj, cols across lane&15)
#pragma unroll
    for (int jj = 0; jj < 4; jj++) {
      float mx = fmaxf(fmaxf(sv[0][jj], sv[1][jj]), fmaxf(sv[2][jj], sv[3][jj]));
      mx = fmaxf(mx, __shfl_xor(mx, 1, 64));
      mx = fmaxf(mx, __shfl_xor(mx, 2, 64));
      mx = fmaxf(mx, __shfl_xor(mx, 4, 64));
      mx = fmaxf(mx, __shfl_xor(mx, 8, 64));
      const float mn = fmaxf(m_r[jj], mx);
      const float sc = __expf(m_r[jj] - mn);
      m_r[jj] = mn;
      l_r[jj] *= sc;
#pragma unroll
      for (int df = 0; df < 8; df++) oacc[df][jj] *= sc;
      float rs = 0.f;
#pragma unroll
      for (int kc = 0; kc < 4; kc++) {
        const float p = __expf(sv[kc][jj] - mn);
        rs += p;
        Pl[w][g * 4 + jj][kc * 16 + lo] = (bf16_t)p;
      }
      rs += __shfl_xor(rs, 1, 64);
      rs += __shfl_xor(rs, 2, 64);
      rs += __shfl_xor(rs, 4, 64);
      rs += __shfl_xor(rs, 8, 64);
      l_r[jj] += rs;
    }

    __syncthreads();   // Vt staged (all waves) + P writes drained

    // ---- PV: oacc += P(16x64) * V(64x128)
#pragma unroll
    for (int ks = 0; ks < 2; ++ks) {
      bf16x8 pa = *(const bf16x8*)&Pl[w][lo][ks * 32 + g * 8];
#pragma unroll
      for (int df = 0; df < 8; df++) {
        bf16x8 vf = *(const bf16x8*)&Vt[df * 16 + lo][ks * 32 + g * 8];
        oacc[df] = mfma16(pa, vf, oacc[df]);
      }
    }
    __syncthreads();   // protect Vt before next-tile staging
  }

  // ---- finalize: divide by l, write ctx [S][H] bf16
#pragma unroll
  for (int jj = 0; jj < 4; jj++) {
    const float inv = 1.0f / l_r[jj];
    const int r = q_base + g * 4 + jj;
#pragma unroll
    for (int df = 0; df < 8; df++) {
      const int d = df * 16 + lo;
      ctx[(size_t)r * H_DIM + h * HD + d] = (bf16_t)(oacc[df][jj] * inv);
    }
  }
}

// ---------------- launch ----------------
extern "C" void kernel_launch(void* const* d_in, const int* in_sizes, int n_in,
                              void* d_out, int out_size, void* d_ws, size_t ws_size,
                              hipStream_t stream) {
  const float* hidden   = (const float*)d_in[0];
  const float* residual = (const float*)d_in[1];
  const float* alibi    = (const float*)d_in[2];
  // d_in[3] attention_mask: analytic (triu k=1 == causal), unused
  const float* w_qkv    = (const float*)d_in[4];
  const float* b_qkv    = (const float*)d_in[5];
  const float* w_dense  = (const float*)d_in[6];
  const float* b_dense  = (const float*)d_in[7];
  float* out = (float*)d_out;

  char* ws = (char*)d_ws;
  // layout (bytes): total 218,103,808
  bf16_t* Xb  = (bf16_t*)(ws);                 // 2048*4096*2      = 16,777,216
  bf16_t* Wqb = (bf16_t*)(ws + 16777216);      // 12288*4096*2     = 100,663,296
  bf16_t* Wdb = (bf16_t*)(ws + 117440512);     // 4096*4096*2      = 33,554,432
  bf16_t* Qb  = (bf16_t*)(ws + 150994944);     // 32*2048*128*2    = 16,777,216
  bf16_t* Kb  = (bf16_t*)(ws + 167772160);
  bf16_t* Vb  = (bf16_t*)(ws + 184549376);
  bf16_t* Ctx = (bf16_t*)(ws + 201326592);

  // fp32 -> bf16 converts
  {
    int n4 = (S_LEN * H_DIM) / 4;        // 2,097,152
    cvt_f32_bf16<<<(n4 + 255) / 256, 256, 0, stream>>>(hidden, Xb, n4);
  }
  {
    int n4 = (N_QKV * H_DIM) / 4;        // 12,582,912
    cvt_f32_bf16<<<(n4 + 255) / 256, 256, 0, stream>>>(w_qkv, Wqb, n4);
  }
  {
    int n4 = (H_DIM * H_DIM) / 4;        // 4,194,304
    cvt_f32_bf16<<<(n4 + 255) / 256, 256, 0, stream>>>(w_dense, Wdb, n4);
  }

  // QKV GEMM: [2048 x 4096] @ [12288 x 4096]^T -> scatter Q(scaled)/K/V
  gemm_bt<0><<<dim3(N_QKV / 128, S_LEN / 128), 256, 0, stream>>>(
      Xb, Wqb, b_qkv, nullptr, Qb, Kb, Vb, nullptr, H_DIM);

  // attention
  attn_kernel<<<NHEAD * (S_LEN / 64), 256, 0, stream>>>(Qb, Kb, Vb, alibi, Ctx);

  // dense GEMM + bias + residual -> fp32 out
  gemm_bt<1><<<dim3(H_DIM / 128, S_LEN / 128), 256, 0, stream>>>(
      Ctx, Wdb, b_dense, residual, nullptr, nullptr, nullptr, out, H_DIM);
}